// Round 3
// baseline (345.381 us; speedup 1.0000x reference)
//
#include <hip/hip_runtime.h>

// BatchWiseTripletLoss: n=8192 rows, d=128, scalar output.
// K1 normalize->bf16 ws; K2 MFMA pass computing per-row max_neg/max_pos
// (partials over SPLIT column ranges x 2 column-half waves); K3 combine
// maxima; K4 MFMA pass accumulating thresholded loss; K5a/K5b final reduce.

#define D 128
#define BM 128
#define BN 128
#define SPLIT 16
#define NPART (SPLIT * 2)  // blockIdx.y x wc column-half partials
#define MARGIN 0.1f
#define NEG_FLOOR 0.6f
#define NINF -1e30f

typedef short bf16x8 __attribute__((ext_vector_type(8)));
typedef float f32x4 __attribute__((ext_vector_type(4)));

__device__ __forceinline__ unsigned short f2bf(float f) {
  unsigned u = __float_as_uint(f);
  u += 0x7FFFu + ((u >> 16) & 1u);
  return (unsigned short)(u >> 16);
}

// ---- K1: L2-normalize rows, emit bf16 ----
__global__ void k_normalize(const float* __restrict__ emb,
                            unsigned short* __restrict__ eb, int n) {
  int wave = threadIdx.x >> 6;
  int lane = threadIdx.x & 63;
  int row = blockIdx.x * 4 + wave;
  if (row >= n) return;
  float2 v = *(const float2*)(emb + (size_t)row * D + lane * 2);
  float ss = v.x * v.x + v.y * v.y;
#pragma unroll
  for (int off = 1; off < 64; off <<= 1) ss += __shfl_xor(ss, off, 64);
  float inv = 1.0f / fmaxf(sqrtf(ss), 1e-12f);
  unsigned short a = f2bf(v.x * inv);
  unsigned short b = f2bf(v.y * inv);
  *(unsigned int*)(eb + (size_t)row * D + lane * 2) =
      (unsigned)a | ((unsigned)b << 16);
}

// ---- K2/K4: GEMM pass with fused epilogue ----
// PASS 0: running max_neg / max_pos per row -> partials [NPART][n]
// PASS 1: thresholded loss sums per row     -> partials [NPART][n]
template <int PASS>
__global__ __launch_bounds__(256, 4) void k_pass(
    const unsigned short* __restrict__ eb, const int* __restrict__ tgt,
    float* __restrict__ mneg_p, float* __restrict__ mpos_p,
    const float* __restrict__ fneg, const float* __restrict__ fpos,
    float* __restrict__ loss_p, int n) {
  __shared__ char Bs[BN * 256];  // 128 rows x 128 bf16 (256B), chunk-swizzled

  const int tid = threadIdx.x;
  const int lane = tid & 63;
  const int w = tid >> 6;
  const int wr = w >> 1, wc = w & 1;
  const int l15 = lane & 15, g = lane >> 4;

  const int m0 = blockIdx.x * BM;
  const int colsPer = n / SPLIT;
  const int c0base = blockIdx.y * colsPer;
  const int pidx = blockIdx.y * 2 + wc;  // per-column-half partial slot

  // A fragments: this wave's 64 rows x K=128, plus row targets.
  bf16x8 a[4][4];
  int tr[4][4];
#pragma unroll
  for (int mt = 0; mt < 4; ++mt) {
    int rowA = m0 + wr * 64 + mt * 16 + l15;
#pragma unroll
    for (int ks = 0; ks < 4; ++ks)
      a[mt][ks] = *(const bf16x8*)(eb + (size_t)rowA * D + ks * 32 + g * 8);
    int rowT = m0 + wr * 64 + mt * 16 + g * 4;
#pragma unroll
    for (int r = 0; r < 4; ++r) tr[mt][r] = tgt[rowT + r];
  }

  float accN[4][4], accP[4][4], lossAcc[4][4];
  if (PASS == 0) {
#pragma unroll
    for (int mt = 0; mt < 4; ++mt)
#pragma unroll
      for (int r = 0; r < 4; ++r) {
        accN[mt][r] = NINF;
        accP[mt][r] = NINF;
      }
  } else {
#pragma unroll
    for (int mt = 0; mt < 4; ++mt) {
      int rowT = m0 + wr * 64 + mt * 16 + g * 4;
#pragma unroll
      for (int r = 0; r < 4; ++r) {
        accN[mt][r] = fneg[rowT + r] + MARGIN;                    // thr_pos
        accP[mt][r] = fmaxf(NEG_FLOOR, fpos[rowT + r]) - MARGIN;  // thr_neg
        lossAcc[mt][r] = 0.0f;
      }
    }
  }

  const int nIter = colsPer / BN;
  for (int it = 0; it < nIter; ++it) {
    const int c0 = c0base + it * BN;
    // Column targets for this wave's 4 stripes — issue early, complete by
    // the barrier's vmcnt drain.
    int tcv[4];
#pragma unroll
    for (int nt = 0; nt < 4; ++nt)
      tcv[nt] = tgt[c0 + wc * 64 + nt * 16 + l15];
    // Stage B tile (rows c0..c0+127). Linear LDS dest + inverse-swizzled
    // global source; reads below apply the same XOR (involution).
#pragma unroll
    for (int i = 0; i < 8; ++i) {
      int ldsOff = i * 4096 + tid * 16;
      int r = i * 16 + (tid >> 4);
      int csrc = (tid & 15) ^ (r & 7);
      const unsigned short* src = eb + (size_t)(c0 + r) * D + csrc * 8;
      __builtin_amdgcn_global_load_lds(
          (const __attribute__((address_space(1))) void*)src,
          (__attribute__((address_space(3))) void*)(Bs + ldsOff), 16, 0, 0);
    }
    __syncthreads();

#pragma unroll
    for (int nt = 0; nt < 4; ++nt) {
      f32x4 acc[4];
#pragma unroll
      for (int mt = 0; mt < 4; ++mt) acc[mt] = (f32x4){0.f, 0.f, 0.f, 0.f};
      const int lrow = wc * 64 + nt * 16 + l15;
#pragma unroll
      for (int ks = 0; ks < 4; ++ks) {
        int chunk = (ks * 4 + g) ^ (lrow & 7);
        bf16x8 b = *(const bf16x8*)(Bs + lrow * 256 + chunk * 16);
#pragma unroll
        for (int mt = 0; mt < 4; ++mt)
          acc[mt] = __builtin_amdgcn_mfma_f32_16x16x32_bf16(a[mt][ks], b,
                                                            acc[mt], 0, 0, 0);
      }
      // Fused epilogue for this 64x16 column stripe.
      const int tc = tcv[nt];
      const int colTileBase = c0 + wc * 64 + nt * 16;
#pragma unroll
      for (int mt = 0; mt < 4; ++mt) {
        const int rowTileBase = m0 + wr * 64 + mt * 16;
        if (rowTileBase != colTileBase) {  // wave-uniform fast path
#pragma unroll
          for (int r = 0; r < 4; ++r) {
            float s = acc[mt][r];
            bool same = (tr[mt][r] == tc);
            if (PASS == 0) {
              accN[mt][r] = fmaxf(accN[mt][r], same ? NINF : s);
              accP[mt][r] = fmaxf(accP[mt][r], same ? s : NINF);
            } else {
              float v1 = (same && s < accN[mt][r]) ? (1.0f - s) : 0.0f;
              float v2 = (!same && s > accP[mt][r]) ? s : 0.0f;
              lossAcc[mt][r] += v1 + v2;
            }
          }
        } else {  // diagonal tile: exclude self-pair
#pragma unroll
          for (int r = 0; r < 4; ++r) {
            float s = acc[mt][r];
            bool same = (tr[mt][r] == tc);
            bool posOk = same && ((g * 4 + r) != l15);
            if (PASS == 0) {
              accN[mt][r] = fmaxf(accN[mt][r], same ? NINF : s);
              accP[mt][r] = fmaxf(accP[mt][r], posOk ? s : NINF);
            } else {
              float v1 = (posOk && s < accN[mt][r]) ? (1.0f - s) : 0.0f;
              float v2 = (!same && s > accP[mt][r]) ? s : 0.0f;
              lossAcc[mt][r] += v1 + v2;
            }
          }
        }
      }
    }
    __syncthreads();
  }

  // Cross-lane reduce over the 16 lanes sharing each row (lane bits 0..3).
#pragma unroll
  for (int mt = 0; mt < 4; ++mt) {
#pragma unroll
    for (int r = 0; r < 4; ++r) {
      int row = m0 + wr * 64 + mt * 16 + g * 4 + r;
      if (PASS == 0) {
        float vn = accN[mt][r], vp = accP[mt][r];
#pragma unroll
        for (int off = 1; off < 16; off <<= 1) {
          vn = fmaxf(vn, __shfl_xor(vn, off, 64));
          vp = fmaxf(vp, __shfl_xor(vp, off, 64));
        }
        if (l15 == 0) {
          mneg_p[(size_t)pidx * n + row] = vn;
          mpos_p[(size_t)pidx * n + row] = vp;
        }
      } else {
        float vl = lossAcc[mt][r];
#pragma unroll
        for (int off = 1; off < 16; off <<= 1) vl += __shfl_xor(vl, off, 64);
        if (l15 == 0) loss_p[(size_t)pidx * n + row] = vl;
      }
    }
  }
}

// ---- K3: combine NPART partial maxima ----
__global__ void k_combine(const float* __restrict__ mneg_p,
                          const float* __restrict__ mpos_p,
                          float* __restrict__ fneg, float* __restrict__ fpos,
                          int n) {
  int i = blockIdx.x * blockDim.x + threadIdx.x;
  if (i >= n) return;
  float vn = NINF, vp = NINF;
#pragma unroll
  for (int s = 0; s < NPART; ++s) {
    vn = fmaxf(vn, mneg_p[(size_t)s * n + i]);
    vp = fmaxf(vp, mpos_p[(size_t)s * n + i]);
  }
  fneg[i] = vn;
  fpos[i] = vp;
}

// ---- K5a: per-chunk deterministic reduction (32 blocks x 256 rows) ----
__global__ void k_final1(const float* __restrict__ loss_p,
                         const float* __restrict__ fpos,
                         float* __restrict__ bpart, int n) {
  __shared__ float red[256];
  int i = blockIdx.x * 256 + threadIdx.x;
  float acc = 0.f;
  if (fpos[i] > -1e29f) {  // has_pos
#pragma unroll
    for (int sp = 0; sp < NPART; ++sp) acc += loss_p[(size_t)sp * n + i];
  }
  red[threadIdx.x] = acc;
  __syncthreads();
  for (int off = 128; off > 0; off >>= 1) {
    if ((int)threadIdx.x < off) red[threadIdx.x] += red[threadIdx.x + off];
    __syncthreads();
  }
  if (threadIdx.x == 0) bpart[blockIdx.x] = red[0];
}

// ---- K5b: final sum of 32 block partials ----
__global__ void k_final2(const float* __restrict__ bpart,
                         float* __restrict__ out, int n, int nb) {
  int lane = threadIdx.x & 63;
  float v = (lane < nb) ? bpart[lane] : 0.f;
#pragma unroll
  for (int off = 1; off < 64; off <<= 1) v += __shfl_xor(v, off, 64);
  if (lane == 0) out[0] = v / (float)n;
}

extern "C" void kernel_launch(void* const* d_in, const int* in_sizes, int n_in,
                              void* d_out, int out_size, void* d_ws,
                              size_t ws_size, hipStream_t stream) {
  const float* emb = (const float*)d_in[0];
  const int* tgt = (const int*)d_in[1];
  float* out = (float*)d_out;
  const int n = in_sizes[1];  // 8192

  char* ws = (char*)d_ws;
  unsigned short* eb = (unsigned short*)ws;  // bf16 normalized [n][128]
  size_t ebBytes = (size_t)n * D * sizeof(unsigned short);
  float* mneg_p = (float*)(ws + ebBytes);       // [NPART][n]
  float* mpos_p = mneg_p + (size_t)NPART * n;   // [NPART][n]
  float* loss_p = mpos_p + (size_t)NPART * n;   // [NPART][n]
  float* fneg = loss_p + (size_t)NPART * n;     // [n]
  float* fpos = fneg + n;                       // [n]
  float* bpart = fpos + n;                      // [32]

  k_normalize<<<n / 4, 256, 0, stream>>>(emb, eb, n);

  dim3 grid(n / BM, SPLIT);
  k_pass<0><<<grid, 256, 0, stream>>>(eb, tgt, mneg_p, mpos_p, fneg, fpos,
                                      loss_p, n);
  k_combine<<<(n + 255) / 256, 256, 0, stream>>>(mneg_p, mpos_p, fneg, fpos,
                                                 n);
  k_pass<1><<<grid, 256, 0, stream>>>(eb, tgt, mneg_p, mpos_p, fneg, fpos,
                                      loss_p, n);
  k_final1<<<n / 256, 256, 0, stream>>>(loss_p, fpos, bpart, n);
  k_final2<<<1, 64, 0, stream>>>(bpart, out, n, n / 256);
}

// Round 4
// 102.670 us; speedup vs baseline: 3.3640x; 3.3640x over previous
//
#include <hip/hip_runtime.h>

// BatchWiseTripletLoss: n=8192 rows, d=128, scalar output.
// K1 normalize->bf16 ws; K2 MFMA pass computing per-row max_neg/max_pos
// (partials over SPLIT column ranges x 2 column-half waves); K4 MFMA pass
// (with fused partial-max combine) accumulating thresholded loss;
// K5a/K5b deterministic final reduce.
//
// NOTE: __launch_bounds__(256,2) is load-bearing. (256,4) caps arch-VGPRs
// at 64, spills the A fragments, and turns the kernel scratch-BW-bound
// (round 3: FETCH_SIZE 683 MB, 345 us). At (256,2) the compiler uses 128
// VGPR, which naturally allows 4 blocks/CU with the 1024-block grid.

#define D 128
#define BM 128
#define BN 128
#define SPLIT 16
#define NPART (SPLIT * 2)  // blockIdx.y x wc column-half partials
#define MARGIN 0.1f
#define NEG_FLOOR 0.6f
#define NINF -1e30f

typedef short bf16x8 __attribute__((ext_vector_type(8)));
typedef float f32x4 __attribute__((ext_vector_type(4)));

__device__ __forceinline__ unsigned short f2bf(float f) {
  unsigned u = __float_as_uint(f);
  u += 0x7FFFu + ((u >> 16) & 1u);
  return (unsigned short)(u >> 16);
}

// ---- K1: L2-normalize rows, emit bf16 ----
__global__ void k_normalize(const float* __restrict__ emb,
                            unsigned short* __restrict__ eb, int n) {
  int wave = threadIdx.x >> 6;
  int lane = threadIdx.x & 63;
  int row = blockIdx.x * 4 + wave;
  if (row >= n) return;
  float2 v = *(const float2*)(emb + (size_t)row * D + lane * 2);
  float ss = v.x * v.x + v.y * v.y;
#pragma unroll
  for (int off = 1; off < 64; off <<= 1) ss += __shfl_xor(ss, off, 64);
  float inv = 1.0f / fmaxf(sqrtf(ss), 1e-12f);
  unsigned short a = f2bf(v.x * inv);
  unsigned short b = f2bf(v.y * inv);
  *(unsigned int*)(eb + (size_t)row * D + lane * 2) =
      (unsigned)a | ((unsigned)b << 16);
}

// ---- K2/K4: GEMM pass with fused epilogue ----
// PASS 0: running max_neg / max_pos per row -> partials [NPART][n]
// PASS 1: thresholded loss sums per row     -> partials [NPART][n]
//         (combines the PASS-0 partial maxima in its prologue)
template <int PASS>
__global__ __launch_bounds__(256, 2) void k_pass(
    const unsigned short* __restrict__ eb, const int* __restrict__ tgt,
    float* __restrict__ mneg_p, float* __restrict__ mpos_p,
    float* __restrict__ loss_p, int n) {
  __shared__ char Bs[BN * 256];  // 128 rows x 128 bf16 (256B), chunk-swizzled
  __shared__ float thrN[BM], thrP[BM];

  const int tid = threadIdx.x;
  const int lane = tid & 63;
  const int w = tid >> 6;
  const int wr = w >> 1, wc = w & 1;
  const int l15 = lane & 15, g = lane >> 4;

  const int m0 = blockIdx.x * BM;
  const int colsPer = n / SPLIT;
  const int c0base = blockIdx.y * colsPer;
  const int pidx = blockIdx.y * 2 + wc;  // per-column-half partial slot

  // PASS 1 prologue: combine the NPART partial maxima for this block's
  // 128 rows into per-row thresholds (in LDS).
  if (PASS == 1) {
    int r0 = tid & 127, which = tid >> 7;
    const float* src = which ? mpos_p : mneg_p;
    float v = NINF;
#pragma unroll
    for (int s = 0; s < NPART; ++s) v = fmaxf(v, src[(size_t)s * n + m0 + r0]);
    if (which)
      thrP[r0] = fmaxf(NEG_FLOOR, v) - MARGIN;  // thr_neg
    else
      thrN[r0] = v + MARGIN;  // thr_pos
    __syncthreads();
  }

  // A fragments: this wave's 64 rows x K=128, plus row targets.
  bf16x8 a[4][4];
  int tr[4][4];
#pragma unroll
  for (int mt = 0; mt < 4; ++mt) {
    int rowA = m0 + wr * 64 + mt * 16 + l15;
#pragma unroll
    for (int ks = 0; ks < 4; ++ks)
      a[mt][ks] = *(const bf16x8*)(eb + (size_t)rowA * D + ks * 32 + g * 8);
    int rowT = m0 + wr * 64 + mt * 16 + g * 4;
#pragma unroll
    for (int r = 0; r < 4; ++r) tr[mt][r] = tgt[rowT + r];
  }

  float accN[4][4], accP[4][4], lossAcc[4][4];
#pragma unroll
  for (int mt = 0; mt < 4; ++mt) {
    int rl = wr * 64 + mt * 16 + g * 4;
#pragma unroll
    for (int r = 0; r < 4; ++r) {
      if (PASS == 0) {
        accN[mt][r] = NINF;
        accP[mt][r] = NINF;
      } else {
        accN[mt][r] = thrN[rl + r];  // thr_pos
        accP[mt][r] = thrP[rl + r];  // thr_neg
        lossAcc[mt][r] = 0.0f;
      }
    }
  }

  const int nIter = colsPer / BN;
  for (int it = 0; it < nIter; ++it) {
    const int c0 = c0base + it * BN;
    // Column targets for this wave's 4 stripes — issue early.
    int tcv[4];
#pragma unroll
    for (int nt = 0; nt < 4; ++nt) tcv[nt] = tgt[c0 + wc * 64 + nt * 16 + l15];
    // Stage B tile (rows c0..c0+127). Linear LDS dest + inverse-swizzled
    // global source; reads below apply the same XOR (involution).
#pragma unroll
    for (int i = 0; i < 8; ++i) {
      int ldsOff = i * 4096 + tid * 16;
      int r = i * 16 + (tid >> 4);
      int csrc = (tid & 15) ^ (r & 7);
      const unsigned short* src = eb + (size_t)(c0 + r) * D + csrc * 8;
      __builtin_amdgcn_global_load_lds(
          (const __attribute__((address_space(1))) void*)src,
          (__attribute__((address_space(3))) void*)(Bs + ldsOff), 16, 0, 0);
    }
    __syncthreads();

#pragma unroll
    for (int nt = 0; nt < 4; ++nt) {
      f32x4 acc[4];
#pragma unroll
      for (int mt = 0; mt < 4; ++mt) acc[mt] = (f32x4){0.f, 0.f, 0.f, 0.f};
      const int lrow = wc * 64 + nt * 16 + l15;
#pragma unroll
      for (int ks = 0; ks < 4; ++ks) {
        int chunk = (ks * 4 + g) ^ (lrow & 7);
        bf16x8 b = *(const bf16x8*)(Bs + lrow * 256 + chunk * 16);
#pragma unroll
        for (int mt = 0; mt < 4; ++mt)
          acc[mt] = __builtin_amdgcn_mfma_f32_16x16x32_bf16(a[mt][ks], b,
                                                            acc[mt], 0, 0, 0);
      }
      // Fused epilogue for this 64x16 column stripe.
      const int tc = tcv[nt];
      const int colTileBase = c0 + wc * 64 + nt * 16;
#pragma unroll
      for (int mt = 0; mt < 4; ++mt) {
        const int rowTileBase = m0 + wr * 64 + mt * 16;
        if (rowTileBase != colTileBase) {  // wave-uniform fast path
#pragma unroll
          for (int r = 0; r < 4; ++r) {
            float s = acc[mt][r];
            bool same = (tr[mt][r] == tc);
            if (PASS == 0) {
              accN[mt][r] = fmaxf(accN[mt][r], same ? NINF : s);
              accP[mt][r] = fmaxf(accP[mt][r], same ? s : NINF);
            } else {
              float v1 = (same && s < accN[mt][r]) ? (1.0f - s) : 0.0f;
              float v2 = (!same && s > accP[mt][r]) ? s : 0.0f;
              lossAcc[mt][r] += v1 + v2;
            }
          }
        } else {  // diagonal tile: exclude self-pair
#pragma unroll
          for (int r = 0; r < 4; ++r) {
            float s = acc[mt][r];
            bool same = (tr[mt][r] == tc);
            bool posOk = same && ((g * 4 + r) != l15);
            if (PASS == 0) {
              accN[mt][r] = fmaxf(accN[mt][r], same ? NINF : s);
              accP[mt][r] = fmaxf(accP[mt][r], posOk ? s : NINF);
            } else {
              float v1 = (posOk && s < accN[mt][r]) ? (1.0f - s) : 0.0f;
              float v2 = (!same && s > accP[mt][r]) ? s : 0.0f;
              lossAcc[mt][r] += v1 + v2;
            }
          }
        }
      }
    }
    __syncthreads();
  }

  // Cross-lane reduce over the 16 lanes sharing each row (lane bits 0..3).
#pragma unroll
  for (int mt = 0; mt < 4; ++mt) {
#pragma unroll
    for (int r = 0; r < 4; ++r) {
      int row = m0 + wr * 64 + mt * 16 + g * 4 + r;
      if (PASS == 0) {
        float vn = accN[mt][r], vp = accP[mt][r];
#pragma unroll
        for (int off = 1; off < 16; off <<= 1) {
          vn = fmaxf(vn, __shfl_xor(vn, off, 64));
          vp = fmaxf(vp, __shfl_xor(vp, off, 64));
        }
        if (l15 == 0) {
          mneg_p[(size_t)pidx * n + row] = vn;
          mpos_p[(size_t)pidx * n + row] = vp;
        }
      } else {
        float vl = lossAcc[mt][r];
#pragma unroll
        for (int off = 1; off < 16; off <<= 1) vl += __shfl_xor(vl, off, 64);
        if (l15 == 0) loss_p[(size_t)pidx * n + row] = vl;
      }
    }
  }
}

// ---- K5a: per-chunk deterministic reduction (32 blocks x 256 rows) ----
__global__ void k_final1(const float* __restrict__ loss_p,
                         const float* __restrict__ mpos_p,
                         float* __restrict__ bpart, int n) {
  __shared__ float red[256];
  int i = blockIdx.x * 256 + threadIdx.x;
  float vp = NINF, acc = 0.f;
#pragma unroll
  for (int sp = 0; sp < NPART; ++sp) {
    vp = fmaxf(vp, mpos_p[(size_t)sp * n + i]);
    acc += loss_p[(size_t)sp * n + i];
  }
  acc = (vp > -1e29f) ? acc : 0.f;  // has_pos
  red[threadIdx.x] = acc;
  __syncthreads();
  for (int off = 128; off > 0; off >>= 1) {
    if ((int)threadIdx.x < off) red[threadIdx.x] += red[threadIdx.x + off];
    __syncthreads();
  }
  if (threadIdx.x == 0) bpart[blockIdx.x] = red[0];
}

// ---- K5b: final sum of 32 block partials ----
__global__ void k_final2(const float* __restrict__ bpart,
                         float* __restrict__ out, int n, int nb) {
  int lane = threadIdx.x & 63;
  float v = (lane < nb) ? bpart[lane] : 0.f;
#pragma unroll
  for (int off = 1; off < 64; off <<= 1) v += __shfl_xor(v, off, 64);
  if (lane == 0) out[0] = v / (float)n;
}

extern "C" void kernel_launch(void* const* d_in, const int* in_sizes, int n_in,
                              void* d_out, int out_size, void* d_ws,
                              size_t ws_size, hipStream_t stream) {
  const float* emb = (const float*)d_in[0];
  const int* tgt = (const int*)d_in[1];
  float* out = (float*)d_out;
  const int n = in_sizes[1];  // 8192

  char* ws = (char*)d_ws;
  unsigned short* eb = (unsigned short*)ws;  // bf16 normalized [n][128]
  size_t ebBytes = (size_t)n * D * sizeof(unsigned short);
  float* mneg_p = (float*)(ws + ebBytes);      // [NPART][n]
  float* mpos_p = mneg_p + (size_t)NPART * n;  // [NPART][n]
  float* loss_p = mpos_p + (size_t)NPART * n;  // [NPART][n]
  float* bpart = loss_p + (size_t)NPART * n;   // [32]

  k_normalize<<<n / 4, 256, 0, stream>>>(emb, eb, n);

  dim3 grid(n / BM, SPLIT);
  k_pass<0><<<grid, 256, 0, stream>>>(eb, tgt, mneg_p, mpos_p, loss_p, n);
  k_pass<1><<<grid, 256, 0, stream>>>(eb, tgt, mneg_p, mpos_p, loss_p, n);
  k_final1<<<n / 256, 256, 0, stream>>>(loss_p, mpos_p, bpart, n);
  k_final2<<<1, 64, 0, stream>>>(bpart, out, n, n / 256);
}

// Round 5
// 94.770 us; speedup vs baseline: 3.6444x; 1.0834x over previous
//
#include <hip/hip_runtime.h>

// BatchWiseTripletLoss: n=8192 rows, d=128, scalar output.
// Round-5 structure: store normalized bf16 matrix in MFMA *fragment order*
// (ebB[stripe][ks][lane]), so both A- and B-fragment loads are coalesced
// 1KB wave loads straight from L2/L1. No LDS staging, no barriers in the
// GEMM passes, free-running waves. (Round 4 showed the stage->barrier
// lockstep at 2 blocks/CU left the machine ~75% idle.)
//
// K1 normalize -> ebB; K2 pass0 per-row max_neg/max_pos partials [SPLIT][n];
// K3 combine; K4 pass1 thresholded loss partials; K5a/K5b final reduce.

#define D 128
#define BM 256  // rows per block = 4 waves x 64
#define SPLIT 32
#define NPART SPLIT
#define MARGIN 0.1f
#define NEG_FLOOR 0.6f
#define NINF -1e30f

typedef short bf16x8 __attribute__((ext_vector_type(8)));
typedef float f32x4 __attribute__((ext_vector_type(4)));

__device__ __forceinline__ unsigned short f2bf(float f) {
  unsigned u = __float_as_uint(f);
  u += 0x7FFFu + ((u >> 16) & 1u);
  return (unsigned short)(u >> 16);
}

// ---- K1: L2-normalize rows, emit bf16 in fragment order ----
// ebB chunk (16B = 8 bf16) at [(stripe*4 + ks)*64 + lane] holds
// row = stripe*16 + (lane&15), elements [(ks*4 + (lane>>4))*8 .. +8).
__global__ void k_normB(const float* __restrict__ emb,
                        uint4* __restrict__ ebB, int n) {
  const int s = blockIdx.x;           // 16-row stripe
  const int rl = threadIdx.x >> 4;    // row within stripe (0..15)
  const int c = threadIdx.x & 15;     // 16B chunk within row (0..15)
  const int row = s * 16 + rl;
  const float* p = emb + (size_t)row * D + c * 8;
  float4 v0 = *(const float4*)p;
  float4 v1 = *(const float4*)(p + 4);
  float ss = v0.x * v0.x + v0.y * v0.y + v0.z * v0.z + v0.w * v0.w +
             v1.x * v1.x + v1.y * v1.y + v1.z * v1.z + v1.w * v1.w;
  // Reduce over the 16 lanes holding this row (lanes share bits 4..5).
#pragma unroll
  for (int off = 1; off < 16; off <<= 1) ss += __shfl_xor(ss, off, 64);
  float inv = 1.0f / fmaxf(sqrtf(ss), 1e-12f);
  uint4 wv;
  wv.x = (unsigned)f2bf(v0.x * inv) | ((unsigned)f2bf(v0.y * inv) << 16);
  wv.y = (unsigned)f2bf(v0.z * inv) | ((unsigned)f2bf(v0.w * inv) << 16);
  wv.z = (unsigned)f2bf(v1.x * inv) | ((unsigned)f2bf(v1.y * inv) << 16);
  wv.w = (unsigned)f2bf(v1.z * inv) | ((unsigned)f2bf(v1.w * inv) << 16);
  const int ks = c >> 2, g = c & 3;
  ebB[((s * 4 + ks) * 64) + (g * 16 + rl)] = wv;
}

// ---- K2/K4: barrier-free GEMM pass with fused epilogue ----
template <int PASS>
__global__ __launch_bounds__(256, 2) void k_pass2(
    const bf16x8* __restrict__ ebB, const int* __restrict__ tgt,
    float* __restrict__ mneg_p, float* __restrict__ mpos_p,
    const float* __restrict__ fneg, const float* __restrict__ fpos,
    float* __restrict__ loss_p, int n) {
  const int lane = threadIdx.x & 63;
  const int w = threadIdx.x >> 6;
  const int l15 = lane & 15, g = lane >> 4;

  const int m0 = blockIdx.x * BM;
  const int rbase = m0 + w * 64;  // this wave's 64-row panel
  const int sA = rbase >> 4;      // row stripe index base
  const int colsPer = n / SPLIT;  // 256
  const int c0 = blockIdx.y * colsPer;
  const int pidx = blockIdx.y;

  // A fragments: 16 coalesced 1KB wave loads.
  bf16x8 a[4][4];
#pragma unroll
  for (int mt = 0; mt < 4; ++mt)
#pragma unroll
    for (int ks = 0; ks < 4; ++ks)
      a[mt][ks] = ebB[((sA + mt) * 4 + ks) * 64 + lane];

  // Row targets (int4 per mt; all l15 lanes broadcast the same 16B).
  int tr[4][4];
#pragma unroll
  for (int mt = 0; mt < 4; ++mt) {
    int4 t4 = *(const int4*)(tgt + rbase + mt * 16 + g * 4);
    tr[mt][0] = t4.x; tr[mt][1] = t4.y; tr[mt][2] = t4.z; tr[mt][3] = t4.w;
  }

  float accN[4][4], accP[4][4], lossA[4][4];
#pragma unroll
  for (int mt = 0; mt < 4; ++mt) {
    if (PASS == 0) {
#pragma unroll
      for (int r = 0; r < 4; ++r) {
        accN[mt][r] = NINF;
        accP[mt][r] = NINF;
      }
    } else {
      f32x4 vN = *(const f32x4*)(fneg + rbase + mt * 16 + g * 4);
      f32x4 vP = *(const f32x4*)(fpos + rbase + mt * 16 + g * 4);
#pragma unroll
      for (int r = 0; r < 4; ++r) {
        accN[mt][r] = vN[r] + MARGIN;                    // thr_pos
        accP[mt][r] = fmaxf(NEG_FLOOR, vP[r]) - MARGIN;  // thr_neg
        lossA[mt][r] = 0.0f;
      }
    }
  }

  const int nS = colsPer / 16;  // 16 column stripes
  for (int si = 0; si < nS; ++si) {
    const int cs = (c0 >> 4) + si;
    bf16x8 b[4];
#pragma unroll
    for (int ks = 0; ks < 4; ++ks) b[ks] = ebB[(cs * 4 + ks) * 64 + lane];
    const int tc = tgt[cs * 16 + l15];

    f32x4 acc[4];
#pragma unroll
    for (int mt = 0; mt < 4; ++mt) acc[mt] = (f32x4){0.f, 0.f, 0.f, 0.f};
#pragma unroll
    for (int ks = 0; ks < 4; ++ks)
#pragma unroll
      for (int mt = 0; mt < 4; ++mt)
        acc[mt] = __builtin_amdgcn_mfma_f32_16x16x32_bf16(a[mt][ks], b[ks],
                                                          acc[mt], 0, 0, 0);

#pragma unroll
    for (int mt = 0; mt < 4; ++mt) {
      if (rbase + mt * 16 != cs * 16) {  // off-diagonal: wave-uniform fast path
#pragma unroll
        for (int r = 0; r < 4; ++r) {
          float s = acc[mt][r];
          bool same = (tr[mt][r] == tc);
          if (PASS == 0) {
            accN[mt][r] = fmaxf(accN[mt][r], same ? NINF : s);
            accP[mt][r] = fmaxf(accP[mt][r], same ? s : NINF);
          } else {
            float u = same ? 1.0f - s : s;
            bool c = same ? (s < accN[mt][r]) : (s > accP[mt][r]);
            lossA[mt][r] += c ? u : 0.f;
          }
        }
      } else {  // diagonal tile: exclude self-pair
#pragma unroll
        for (int r = 0; r < 4; ++r) {
          float s = acc[mt][r];
          bool same = (tr[mt][r] == tc);
          bool self = (g * 4 + r) == l15;
          bool posOk = same && !self;
          if (PASS == 0) {
            accN[mt][r] = fmaxf(accN[mt][r], same ? NINF : s);
            accP[mt][r] = fmaxf(accP[mt][r], posOk ? s : NINF);
          } else {
            bool cpos = posOk && (s < accN[mt][r]);
            bool cneg = !same && (s > accP[mt][r]);
            lossA[mt][r] += cpos ? (1.0f - s) : (cneg ? s : 0.f);
          }
        }
      }
    }
  }

  // Reduce over the 16 l15-lanes sharing each row; lane l15==0 writes.
#pragma unroll
  for (int mt = 0; mt < 4; ++mt) {
#pragma unroll
    for (int r = 0; r < 4; ++r) {
      int row = rbase + mt * 16 + g * 4 + r;
      if (PASS == 0) {
        float vn = accN[mt][r], vp = accP[mt][r];
#pragma unroll
        for (int off = 1; off < 16; off <<= 1) {
          vn = fmaxf(vn, __shfl_xor(vn, off, 64));
          vp = fmaxf(vp, __shfl_xor(vp, off, 64));
        }
        if (l15 == 0) {
          mneg_p[(size_t)pidx * n + row] = vn;
          mpos_p[(size_t)pidx * n + row] = vp;
        }
      } else {
        float vl = lossA[mt][r];
#pragma unroll
        for (int off = 1; off < 16; off <<= 1) vl += __shfl_xor(vl, off, 64);
        if (l15 == 0) loss_p[(size_t)pidx * n + row] = vl;
      }
    }
  }
}

// ---- K3: combine NPART partial maxima ----
__global__ void k_combine(const float* __restrict__ mneg_p,
                          const float* __restrict__ mpos_p,
                          float* __restrict__ fneg, float* __restrict__ fpos,
                          int n) {
  int i = blockIdx.x * blockDim.x + threadIdx.x;
  if (i >= n) return;
  float vn = NINF, vp = NINF;
#pragma unroll
  for (int s = 0; s < NPART; ++s) {
    vn = fmaxf(vn, mneg_p[(size_t)s * n + i]);
    vp = fmaxf(vp, mpos_p[(size_t)s * n + i]);
  }
  fneg[i] = vn;
  fpos[i] = vp;
}

// ---- K5a: per-chunk deterministic reduction (32 blocks x 256 rows) ----
__global__ void k_final1(const float* __restrict__ loss_p,
                         const float* __restrict__ fpos,
                         float* __restrict__ bpart, int n) {
  __shared__ float red[256];
  int i = blockIdx.x * 256 + threadIdx.x;
  float acc = 0.f;
  if (fpos[i] > -1e29f) {  // has_pos
#pragma unroll
    for (int sp = 0; sp < NPART; ++sp) acc += loss_p[(size_t)sp * n + i];
  }
  red[threadIdx.x] = acc;
  __syncthreads();
  for (int off = 128; off > 0; off >>= 1) {
    if ((int)threadIdx.x < off) red[threadIdx.x] += red[threadIdx.x + off];
    __syncthreads();
  }
  if (threadIdx.x == 0) bpart[blockIdx.x] = red[0];
}

// ---- K5b: final sum of block partials ----
__global__ void k_final2(const float* __restrict__ bpart,
                         float* __restrict__ out, int n, int nb) {
  int lane = threadIdx.x & 63;
  float v = (lane < nb) ? bpart[lane] : 0.f;
#pragma unroll
  for (int off = 1; off < 64; off <<= 1) v += __shfl_xor(v, off, 64);
  if (lane == 0) out[0] = v / (float)n;
}

extern "C" void kernel_launch(void* const* d_in, const int* in_sizes, int n_in,
                              void* d_out, int out_size, void* d_ws,
                              size_t ws_size, hipStream_t stream) {
  const float* emb = (const float*)d_in[0];
  const int* tgt = (const int*)d_in[1];
  float* out = (float*)d_out;
  const int n = in_sizes[1];  // 8192

  char* ws = (char*)d_ws;
  uint4* ebB = (uint4*)ws;  // fragment-ordered bf16 [n*D*2 bytes]
  size_t ebBytes = (size_t)n * D * sizeof(unsigned short);
  float* mneg_p = (float*)(ws + ebBytes);      // [NPART][n]
  float* mpos_p = mneg_p + (size_t)NPART * n;  // [NPART][n]
  float* loss_p = mpos_p + (size_t)NPART * n;  // [NPART][n]
  float* fneg = loss_p + (size_t)NPART * n;    // [n]
  float* fpos = fneg + n;                      // [n]
  float* bpart = fpos + n;                     // [32]

  k_normB<<<n / 16, 256, 0, stream>>>(emb, ebB, n);

  dim3 grid(n / BM, SPLIT);
  k_pass2<0><<<grid, 256, 0, stream>>>((const bf16x8*)ebB, tgt, mneg_p,
                                       mpos_p, fneg, fpos, loss_p, n);
  k_combine<<<(n + 255) / 256, 256, 0, stream>>>(mneg_p, mpos_p, fneg, fpos,
                                                 n);
  k_pass2<1><<<grid, 256, 0, stream>>>((const bf16x8*)ebB, tgt, mneg_p,
                                       mpos_p, fneg, fpos, loss_p, n);
  k_final1<<<n / 256, 256, 0, stream>>>(loss_p, fpos, bpart, n);
  k_final2<<<1, 64, 0, stream>>>(bpart, out, n, n / 256);
}